// Round 11
// baseline (1346.466 us; speedup 1.0000x reference)
//
#include <hip/hip_runtime.h>

typedef unsigned short ushort;
typedef unsigned int uint;
typedef float f32x4 __attribute__((ext_vector_type(4)));
typedef __bf16 bf16x8 __attribute__((ext_vector_type(8)));
typedef ushort u16x4 __attribute__((ext_vector_type(4)));
typedef ushort u16x8 __attribute__((ext_vector_type(8)));

#define LOG2E 1.4426950408889634f

__device__ __forceinline__ ushort f2bu(float f) { __bf16 b = (__bf16)f; return __builtin_bit_cast(ushort, b); }
__device__ __forceinline__ float  bu2f(ushort u) { return (float)__builtin_bit_cast(__bf16, u); }

__device__ __forceinline__ void gld16(const void* g, void* l) {
    __builtin_amdgcn_global_load_lds((const __attribute__((address_space(1))) unsigned int*)g,
                                     (__attribute__((address_space(3))) unsigned int*)l, 16, 0, 0);
}

// ---------------- convert x fp32 -> bf16 ----------------
__global__ __launch_bounds__(256) void k_cvt(const float* __restrict__ in, ushort* __restrict__ out, int n4) {
    int i = blockIdx.x * 256 + threadIdx.x;
    if (i < n4) {
        float4 v = ((const float4*)in)[i];
        u16x4 o = { f2bu(v.x), f2bu(v.y), f2bu(v.z), f2bu(v.w) };
        ((u16x4*)out)[i] = o;
    }
}

// ---------------- transpose 4 weights fp32 [k][n] -> bf16 [n][k] (z selects) ----------------
__global__ __launch_bounds__(256) void k_twt4(const float* __restrict__ W0, const float* __restrict__ W1,
                                              const float* __restrict__ W2, const float* __restrict__ W3,
                                              ushort* __restrict__ D0, ushort* __restrict__ D1,
                                              ushort* __restrict__ D2, ushort* __restrict__ D3) {
    int z = blockIdx.z;
    const float* W = (z == 0) ? W0 : (z == 1) ? W1 : (z == 2) ? W2 : W3;
    ushort* Wt = (z == 0) ? D0 : (z == 1) ? D1 : (z == 2) ? D2 : D3;
    __shared__ float t[32][33];
    int n0 = blockIdx.x * 32, k0 = blockIdx.y * 32;
    int tx = threadIdx.x & 31, ty = threadIdx.x >> 5;
#pragma unroll
    for (int i = 0; i < 32; i += 8) t[ty + i][tx] = W[(size_t)(k0 + ty + i) * 2048 + n0 + tx];
    __syncthreads();
#pragma unroll
    for (int i = 0; i < 32; i += 8) Wt[(size_t)(n0 + ty + i) * 2048 + k0 + tx] = f2bu(t[tx][ty + i]);
}

// ---------------- rope cos/sin table [4096][32][2] ----------------
__global__ __launch_bounds__(256) void k_rope(float* __restrict__ tab) {
    int idx = blockIdx.x * 256 + threadIdx.x;   // 131072 total
    int t = idx >> 5, j = idx & 31;
    float fr = exp2f(-10.0f * (float)j / 31.0f);      // (1/1024)^(j/31)
    float th = (float)t * fr;
    tab[idx * 2]     = cosf(th);
    tab[idx * 2 + 1] = sinf(th);
}

// ============ 256x256 8-phase bf16 GEMM (m201 template, plain HIP) ============
// MODE 0: QKV merged (N=6144), fused epilogue v1 (measured-best: row-major
//   XOR-swizzled LDS, 492 us in r6). n-panel XCD map: nt = xcd + (local%3)*8.
// MODE 1: Wo (N=2048, f32 out), proven map m = xcd*8 + local>>3, n = local&7.
// K-loop (proven): BK=64 two kh halves, 8 waves (2Mx4N), LDS 128 KiB,
// staging swizzle chunk ^= (row>>1)&3, counted vmcnt(8) at ph2/ph4 tails.
#define AOFF(buf, kh) ((buf) * 32768 + (kh) * 16384)
#define BOFF(buf, kh) (65536 + (buf) * 32768 + (kh) * 16384)

#define STG_A(BUFX, KHX, KKX) do {                                                 \
    gld16(asrc0 + ((KKX) + (KHX) * 32) * 2, lds + AOFF(BUFX, KHX) + ldst);         \
    gld16(asrc1 + ((KKX) + (KHX) * 32) * 2, lds + AOFF(BUFX, KHX) + 8192 + ldst);  \
} while (0)
#define STG_B(BUFX, KHX, KKX) do {                                                 \
    gld16(bsrc0 + ((KKX) + (KHX) * 32) * 2, lds + BOFF(BUFX, KHX) + ldst);         \
    gld16(bsrc1 + ((KKX) + (KHX) * 32) * 2, lds + BOFF(BUFX, KHX) + 8192 + ldst);  \
} while (0)

#define PHASE(BUF, KH, MH, LDB, STAGE_STMT, TAILVM) do {                           \
    bf16x8 af_[4];                                                                 \
    const char* ab_ = lds + AOFF(BUF, KH);                                         \
    _Pragma("unroll")                                                              \
    for (int mi_ = 0; mi_ < 4; ++mi_)                                              \
        af_[mi_] = *(const bf16x8*)(ab_ + offA[(MH) * 4 + mi_]);                   \
    if (LDB) {                                                                     \
        const char* bb_ = lds + BOFF(BUF, KH);                                     \
        _Pragma("unroll")                                                          \
        for (int ni_ = 0; ni_ < 4; ++ni_)                                          \
            bfr[ni_] = *(const bf16x8*)(bb_ + offB[ni_]);                          \
    }                                                                              \
    STAGE_STMT;                                                                    \
    __builtin_amdgcn_s_barrier();                                                  \
    asm volatile("s_waitcnt lgkmcnt(0)" ::: "memory");                             \
    __builtin_amdgcn_sched_barrier(0);                                             \
    __builtin_amdgcn_s_setprio(1);                                                 \
    _Pragma("unroll")                                                              \
    for (int mi_ = 0; mi_ < 4; ++mi_)                                              \
        _Pragma("unroll")                                                          \
        for (int ni_ = 0; ni_ < 4; ++ni_)                                          \
            acc[(MH) * 4 + mi_][ni_] = __builtin_amdgcn_mfma_f32_16x16x32_bf16(    \
                af_[mi_], bfr[ni_], acc[(MH) * 4 + mi_][ni_], 0, 0, 0);            \
    __builtin_amdgcn_s_setprio(0);                                                 \
    TAILVM;                                                                        \
    __builtin_amdgcn_s_barrier();                                                  \
} while (0)

#define TILE(BUF, TC) do {                                                         \
    int tp1_ = (TC) + 1 < 32 ? (TC) + 1 : 31;                                      \
    int tp2_ = (TC) + 2 < 32 ? (TC) + 2 : 31;                                      \
    int kb1_ = tp1_ * 64, kb2_ = tp2_ * 64;                                        \
    PHASE(BUF, 0, 0, 1, STG_A((BUF) ^ 1, 1, kb1_), ((void)0));                     \
    PHASE(BUF, 0, 1, 0, STG_B((BUF) ^ 1, 1, kb1_),                                 \
          asm volatile("s_waitcnt vmcnt(8)" ::: "memory"));                        \
    PHASE(BUF, 1, 0, 1, STG_A(BUF, 0, kb2_), ((void)0));                           \
    PHASE(BUF, 1, 1, 0, STG_B(BUF, 0, kb2_),                                       \
          asm volatile("s_waitcnt vmcnt(8)" ::: "memory"));                        \
} while (0)

template <int MODE>
__global__ __launch_bounds__(512, 2) void k_gemm(const ushort* __restrict__ A, const ushort* __restrict__ Bt,
                                                 const float* __restrict__ rt, float* __restrict__ Cf,
                                                 ushort* __restrict__ qa, ushort* __restrict__ ka,
                                                 ushort* __restrict__ kTa, ushort* __restrict__ vTa) {
    __shared__ __align__(128) char lds[131072];
    const int tid = threadIdx.x;
    const int wid = tid >> 6, lane = tid & 63;
    const int wm = wid >> 2, wn = wid & 3;
    const int lrow = lane & 15, q = lane >> 4;

    int bid = blockIdx.x;
    int xcd = bid & 7, local = bid >> 3;
    int nt, mloc;
    if (MODE == 0) { nt = xcd + (local % 3) * 8; mloc = local / 3; }
    else           { nt = local & 7;             mloc = xcd * 8 + (local >> 3); }
    const size_t n0 = (size_t)nt * 256;
    const size_t m0 = (size_t)mloc * 256;

    // per-thread fragment ds_read byte offsets (staging swizzle)
    int offA[8], offB[4];
#pragma unroll
    for (int mi = 0; mi < 8; ++mi) {
        int R = wm * 128 + mi * 16 + lrow;
        offA[mi] = R * 64 + ((q ^ ((R >> 1) & 3)) << 4);
    }
#pragma unroll
    for (int ni = 0; ni < 4; ++ni) {
        int R = wn * 64 + ni * 16 + lrow;
        offB[ni] = R * 64 + ((q ^ ((R >> 1) & 3)) << 4);
    }

    int srow0 = tid >> 2;
    int cw = (tid & 3) ^ ((tid >> 3) & 3);
    const char* asrc0 = (const char*)(A + (m0 + srow0) * 2048 + cw * 8);
    const char* asrc1 = (const char*)(A + (m0 + srow0 + 128) * 2048 + cw * 8);
    const char* bsrc0 = (const char*)(Bt + (n0 + srow0) * 2048 + cw * 8);
    const char* bsrc1 = (const char*)(Bt + (n0 + srow0 + 128) * 2048 + cw * 8);
    const int ldst = tid * 16;

    f32x4 acc[8][4] = {};
    bf16x8 bfr[4];

    STG_A(0, 0, 0); STG_B(0, 0, 0); STG_A(0, 1, 0); STG_B(0, 1, 0);
    STG_A(1, 0, 64); STG_B(1, 0, 64);
    asm volatile("s_waitcnt vmcnt(8)" ::: "memory");
    __builtin_amdgcn_s_barrier();

#pragma unroll 1
    for (int t = 0; t < 32; t += 2) {
        TILE(0, t);
        TILE(1, t + 1);
    }

    if (MODE == 1) {
#pragma unroll
        for (int mi = 0; mi < 8; ++mi)
#pragma unroll
            for (int ni = 0; ni < 4; ++ni)
#pragma unroll
                for (int i = 0; i < 4; ++i) {
                    size_t row = m0 + wm * 128 + mi * 16 + q * 4 + i;
                    size_t col = n0 + wn * 64 + ni * 16 + lrow;
                    Cf[row * 2048 + col] = acc[mi][ni][i];
                }
        return;
    }

    // ---- MODE 0 fused epilogue v1 (r6, measured-best) ----
    asm volatile("s_waitcnt vmcnt(0)" ::: "memory");   // drain tail gld_lds before LDS reuse
    __syncthreads();
    ushort* ldsu = (ushort*)lds;                        // [128][256] u16, byte ^= (row&7)<<4
    const int tsel = nt >> 3;                           // 0 Q, 1 K, 2 V
    const int b = (int)(m0 >> 12);
    const int tseq0 = (int)(m0 & 4095);
    const int hbase = (nt & 7) * 2;

    for (int st = 0; st < 2; ++st) {
        if (wm == st) {
#pragma unroll
            for (int mi = 0; mi < 8; ++mi)
#pragma unroll
                for (int ni = 0; ni < 4; ++ni)
#pragma unroll
                    for (int i = 0; i < 4; ++i) {
                        int r = mi * 16 + q * 4 + i;
                        int cc = wn * 64 + ni * 16 + lrow;
                        ldsu[((r * 512 + cc * 2) ^ ((r & 7) << 4)) >> 1] = f2bu(acc[mi][ni][i]);
                    }
        }
        __syncthreads();
        if (tsel != 2) {
            // natural layout + rope (pairs d,d+64 rotate for d<32; else identity)
            int rowid = tid >> 1, half = tid & 1;
            int hl = rowid >> 7, r = rowid & 127;
            int t = tseq0 + st * 128 + r;
            int bh = b * 16 + hbase + hl;
            ushort* dstN = (tsel == 0 ? qa : ka) + ((size_t)bh * 4096 + t) * 128;
            int rx = (r & 7) << 4;
#pragma unroll
            for (int j8 = 0; j8 < 4; ++j8) {
                if (half == 0) {
                    int b1 = ((r * 512 + (hl * 128 + j8 * 8) * 2) ^ rx) >> 1;
                    int b2 = ((r * 512 + (hl * 128 + 64 + j8 * 8) * 2) ^ rx) >> 1;
                    u16x8 v1 = *(u16x8*)&ldsu[b1];
                    u16x8 v2 = *(u16x8*)&ldsu[b2];
                    u16x8 o1, o2;
#pragma unroll
                    for (int j = 0; j < 8; ++j) {
                        int d = j8 * 8 + j;
                        float cs = rt[(t * 32 + d) * 2], sn = rt[(t * 32 + d) * 2 + 1];
                        float x1 = bu2f(v1[j]), x2 = bu2f(v2[j]);
                        o1[j] = f2bu(x1 * cs + x2 * sn);
                        o2[j] = f2bu(x2 * cs - x1 * sn);
                    }
                    *(u16x8*)(dstN + j8 * 8) = o1;
                    *(u16x8*)(dstN + 64 + j8 * 8) = o2;
                    if (tsel == 1) {     // write roped back for the transpose pass
                        *(u16x8*)&ldsu[b1] = o1;
                        *(u16x8*)&ldsu[b2] = o2;
                    }
                } else {
                    int b1 = ((r * 512 + (hl * 128 + 32 + j8 * 8) * 2) ^ rx) >> 1;
                    int b2 = ((r * 512 + (hl * 128 + 96 + j8 * 8) * 2) ^ rx) >> 1;
                    u16x8 v1 = *(u16x8*)&ldsu[b1];
                    u16x8 v2 = *(u16x8*)&ldsu[b2];
                    *(u16x8*)(dstN + 32 + j8 * 8) = v1;
                    *(u16x8*)(dstN + 96 + j8 * 8) = v2;
                }
            }
        }
        if (tsel != 0) {
            __syncthreads();            // K: roped rewrite visible; V: harmless
            int drow = tid >> 1, th = tid & 1;
            int hl = drow >> 7, d = drow & 127;
            int bh = b * 16 + hbase + hl;
            float l2r = -exp2f(-0.5f * (float)(hbase + hl + 1)) * LOG2E;
            int t0 = tseq0 + st * 128;  // 128-aligned -> full chunk; s = rr
            ushort* dstT = (tsel == 1 ? kTa : vTa) + ((size_t)bh * 128 + d) * 4096 + t0 + th * 64;
#pragma unroll
            for (int g = 0; g < 8; ++g) {
                u16x8 tmp;
#pragma unroll
                for (int j = 0; j < 8; ++j) {
                    int rr = th * 64 + g * 8 + j;
                    int idx = ((rr * 512 + (hl * 128 + d) * 2) ^ ((rr & 7) << 4)) >> 1;
                    float v = bu2f(ldsu[idx]);
                    if (tsel == 1) v *= exp2f(l2r * (float)(127 - rr));
                    tmp[j] = f2bu(v);
                }
                *(u16x8*)(dstT + g * 8) = tmp;
            }
        }
        __syncthreads();
    }
}

// ---------------- pass1: chunk-local KVt[e][d] -> bf16 ----------------
__global__ __launch_bounds__(256) void k_pass1(const ushort* __restrict__ kTa, const ushort* __restrict__ vTa,
                                               ushort* __restrict__ KVc) {
    int blk = blockIdx.x;           // bh*32 + c
    int c = blk & 31, bh = blk >> 5;
    __shared__ __align__(16) ushort lv[128][136];
    __shared__ __align__(16) ushort lk[128][136];
    int tid = threadIdx.x;
#pragma unroll
    for (int i = 0; i < 8; ++i) {
        int idx = i * 256 + tid; int row = idx >> 4, cb = (idx & 15) * 8;
        *(bf16x8*)&lv[row][cb] = *(const bf16x8*)(vTa + ((size_t)bh * 128 + row) * 4096 + c * 128 + cb);
        *(bf16x8*)&lk[row][cb] = *(const bf16x8*)(kTa + ((size_t)bh * 128 + row) * 4096 + c * 128 + cb);
    }
    __syncthreads();
    int wid = tid >> 6, lane = tid & 63, wr = wid >> 1, wc = wid & 1;
    int lrow = lane & 15, lko = (lane >> 4) * 8;
    f32x4 acc[4][4] = {};
#pragma unroll
    for (int ks = 0; ks < 4; ++ks) {
        bf16x8 a[4], bb[4];
#pragma unroll
        for (int mi = 0; mi < 4; ++mi) a[mi] = *(const bf16x8*)&lv[wr * 64 + mi * 16 + lrow][ks * 32 + lko];
#pragma unroll
        for (int ni = 0; ni < 4; ++ni) bb[ni] = *(const bf16x8*)&lk[wc * 64 + ni * 16 + lrow][ks * 32 + lko];
#pragma unroll
        for (int mi = 0; mi < 4; ++mi)
#pragma unroll
            for (int ni = 0; ni < 4; ++ni)
                acc[mi][ni] = __builtin_amdgcn_mfma_f32_16x16x32_bf16(a[mi], bb[ni], acc[mi][ni], 0, 0, 0);
    }
    ushort* out = KVc + (size_t)blk * 16384;
#pragma unroll
    for (int mi = 0; mi < 4; ++mi)
#pragma unroll
        for (int ni = 0; ni < 4; ++ni)
#pragma unroll
            for (int i = 0; i < 4; ++i)
                out[(wr * 64 + mi * 16 + (lane >> 4) * 4 + i) * 128 + wc * 64 + ni * 16 + lrow] = f2bu(acc[mi][ni][i]);
}

// ---------------- pass2: prefix scan over chunks (fp32 state, bf16 in/out) ----------------
__global__ __launch_bounds__(256) void k_scan(const ushort* __restrict__ KVc, ushort* __restrict__ KVbf) {
    int bh = blockIdx.x >> 4, seg = blockIdx.x & 15, h = bh & 15;
    float slope = exp2f(-0.5f * (float)(h + 1));
    float rC = exp2f(-slope * LOG2E * 128.0f);
    int off = seg * 1024 + threadIdx.x * 4;
    f32x4 st = {0.f, 0.f, 0.f, 0.f};
    for (int c = 0; c < 32; ++c) {
        size_t base = ((size_t)bh * 32 + c) * 16384 + off;
        u16x4 vb = *(const u16x4*)(KVc + base);
        u16x4 o = { f2bu(st.x), f2bu(st.y), f2bu(st.z), f2bu(st.w) };
        *(u16x4*)(KVbf + base) = o;
        st.x = st.x * rC + bu2f(vb[0]);
        st.y = st.y * rC + bu2f(vb[1]);
        st.z = st.z * rC + bu2f(vb[2]);
        st.w = st.w * rC + bu2f(vb[3]);
    }
}

// ---------------- pass3: out = diag(q_decay)*(q@KV) + (dmask o (q@k^T))@v ----------------
__global__ __launch_bounds__(512) void k_pass3(const ushort* __restrict__ qa, const ushort* __restrict__ ka,
                                               const ushort* __restrict__ vTa, const ushort* __restrict__ KVbf,
                                               ushort* __restrict__ attn) {
    int blk = blockIdx.x;           // bh*32 + c
    int c = blk & 31, bh = blk >> 5, h = bh & 15;
    __shared__ __align__(16) ushort lq[128][136];
    __shared__ __align__(16) ushort lk[128][136];   // later reused as P
    __shared__ __align__(16) ushort lv[128][136];
    int tid = threadIdx.x;
#pragma unroll
    for (int i = 0; i < 4; ++i) {
        int idx = i * 512 + tid; int row = idx >> 4, cb = (idx & 15) * 8;
        *(bf16x8*)&lq[row][cb] = *(const bf16x8*)(qa + ((size_t)bh * 4096 + c * 128 + row) * 128 + cb);
        *(bf16x8*)&lk[row][cb] = *(const bf16x8*)(ka + ((size_t)bh * 4096 + c * 128 + row) * 128 + cb);
        *(bf16x8*)&lv[row][cb] = *(const bf16x8*)(vTa + ((size_t)bh * 128 + row) * 4096 + c * 128 + cb);
    }
    __syncthreads();
    int wid = tid >> 6, lane = tid & 63;
    int wr = wid >> 2, wc = wid & 3;          // 2 x 4 wave grid
    int lrow = lane & 15, lko = (lane >> 4) * 8;
    float slope = exp2f(-0.5f * (float)(h + 1));
    float l2r = -slope * LOG2E;

    f32x4 accs[4][2] = {};
#pragma unroll
    for (int kd = 0; kd < 4; ++kd) {
        bf16x8 a[4], bb[2];
#pragma unroll
        for (int mi = 0; mi < 4; ++mi) a[mi] = *(const bf16x8*)&lq[wr * 64 + mi * 16 + lrow][kd * 32 + lko];
#pragma unroll
        for (int ni = 0; ni < 2; ++ni) bb[ni] = *(const bf16x8*)&lk[wc * 32 + ni * 16 + lrow][kd * 32 + lko];
#pragma unroll
        for (int mi = 0; mi < 4; ++mi)
#pragma unroll
            for (int ni = 0; ni < 2; ++ni)
                accs[mi][ni] = __builtin_amdgcn_mfma_f32_16x16x32_bf16(a[mi], bb[ni], accs[mi][ni], 0, 0, 0);
    }
    __syncthreads();

    f32x4 acc[4][2] = {};
#pragma unroll
    for (int kd = 0; kd < 4; ++kd) {
        bf16x8 a[4], bb[2];
#pragma unroll
        for (int mi = 0; mi < 4; ++mi) a[mi] = *(const bf16x8*)&lq[wr * 64 + mi * 16 + lrow][kd * 32 + lko];
#pragma unroll
        for (int ni = 0; ni < 2; ++ni)
            bb[ni] = *(const bf16x8*)(KVbf + (size_t)blk * 16384 + (size_t)(wc * 32 + ni * 16 + lrow) * 128 + kd * 32 + lko);
#pragma unroll
        for (int mi = 0; mi < 4; ++mi)
#pragma unroll
            for (int ni = 0; ni < 2; ++ni)
                acc[mi][ni] = __builtin_amdgcn_mfma_f32_16x16x32_bf16(a[mi], bb[ni], acc[mi][ni], 0, 0, 0);
    }

#pragma unroll
    for (int mi = 0; mi < 4; ++mi)
#pragma unroll
        for (int ni = 0; ni < 2; ++ni)
#pragma unroll
            for (int i = 0; i < 4; ++i) {
                int t = wr * 64 + mi * 16 + (lane >> 4) * 4 + i;
                int s = wc * 32 + ni * 16 + lrow;
                int dt = t - s;
                float w = (dt < 0) ? 0.f : exp2f(l2r * (float)dt);
                lk[t][s] = f2bu(accs[mi][ni][i] * w);
            }

#pragma unroll
    for (int mi = 0; mi < 4; ++mi)
#pragma unroll
        for (int ni = 0; ni < 2; ++ni)
#pragma unroll
            for (int i = 0; i < 4; ++i) {
                int t = wr * 64 + mi * 16 + (lane >> 4) * 4 + i;
                acc[mi][ni][i] *= exp2f(l2r * (float)(t + 1));
            }
    __syncthreads();

#pragma unroll
    for (int ks = 0; ks < 4; ++ks) {
        bf16x8 a[4], bb[2];
#pragma unroll
        for (int mi = 0; mi < 4; ++mi) a[mi] = *(const bf16x8*)&lk[wr * 64 + mi * 16 + lrow][ks * 32 + lko];
#pragma unroll
        for (int ni = 0; ni < 2; ++ni) bb[ni] = *(const bf16x8*)&lv[wc * 32 + ni * 16 + lrow][ks * 32 + lko];
#pragma unroll
        for (int mi = 0; mi < 4; ++mi)
#pragma unroll
            for (int ni = 0; ni < 2; ++ni)
                acc[mi][ni] = __builtin_amdgcn_mfma_f32_16x16x32_bf16(a[mi], bb[ni], acc[mi][ni], 0, 0, 0);
    }

    ushort* out = attn + ((size_t)bh * 4096 + c * 128) * 128;
#pragma unroll
    for (int mi = 0; mi < 4; ++mi)
#pragma unroll
        for (int ni = 0; ni < 2; ++ni)
#pragma unroll
            for (int i = 0; i < 4; ++i)
                out[(size_t)(wr * 64 + mi * 16 + (lane >> 4) * 4 + i) * 128 + wc * 32 + ni * 16 + lrow] =
                    f2bu(acc[mi][ni][i]);
}

// ---------------- RMS norm + [b,h,t,d] -> [token][e] ----------------
__global__ __launch_bounds__(256) void k_rms(const ushort* __restrict__ attn, const float* __restrict__ w,
                                             ushort* __restrict__ normed) {
    int tok = blockIdx.x; int b = tok >> 12, t = tok & 4095;
    int tid = threadIdx.x;
    int e0 = tid * 8; int h = e0 >> 7, d0 = e0 & 127;
    bf16x8 v = *(const bf16x8*)(attn + (((size_t)(b * 16 + h) * 4096 + t) * 128 + d0));
    float f[8]; float ss = 0.f;
#pragma unroll
    for (int j = 0; j < 8; ++j) { f[j] = (float)v[j]; ss += f[j] * f[j]; }
#pragma unroll
    for (int o = 1; o < 64; o <<= 1) ss += __shfl_xor(ss, o, 64);
    __shared__ float red[4];
    if ((tid & 63) == 0) red[tid >> 6] = ss;
    __syncthreads();
    float tot = red[0] + red[1] + red[2] + red[3];
    float sc = rsqrtf(tot * (1.0f / 2048.0f) + 1e-5f);
    u16x8 ov;
#pragma unroll
    for (int j = 0; j < 8; ++j) ov[j] = f2bu(f[j] * sc * w[e0 + j]);
    *(u16x8*)(normed + (size_t)tok * 2048 + e0) = ov;
}

// ---------------- launch ----------------
// ws layout (MiB), lifetime-checked:
//   0-24    WtQKV (Q@0,K@8,V@16)  [twt4 -> QKV gemm]
//   24-32   WtO                   [twt4 -> Wo gemm]
//   32-96   xb [cvt -> QKV gemm] ; attn [pass3 -> rms]
//   96-160  qa  [QKV gemm -> pass3] ; nrm [rms -> Wo gemm]
//   160-224 ka  [QKV gemm -> pass3]
//   224-288 kTa [QKV gemm -> pass1] ; KVbf [scan -> pass3]
//   288-352 vTa [QKV gemm -> pass1,pass3]
//   352-353 rt  [rope -> QKV gemm]
//   353-417 KVc bf16 [pass1 -> scan]
// High-water 417 MiB.
extern "C" void kernel_launch(void* const* d_in, const int* in_sizes, int n_in,
                              void* d_out, int out_size, void* d_ws, size_t ws_size,
                              hipStream_t stream) {
    const float* x    = (const float*)d_in[0];
    const float* Wq   = (const float*)d_in[1];
    const float* Wk   = (const float*)d_in[2];
    const float* Wv   = (const float*)d_in[3];
    const float* Wo   = (const float*)d_in[4];
    const float* rmsw = (const float*)d_in[5];
    char* ws = (char*)d_ws;
    const size_t MiB = 1ull << 20;
    ushort* WtQKV = (ushort*)(ws + 0);
    ushort* WtK   = (ushort*)(ws + 8 * MiB);
    ushort* WtV   = (ushort*)(ws + 16 * MiB);
    ushort* WtO   = (ushort*)(ws + 24 * MiB);
    ushort* xb    = (ushort*)(ws + 32 * MiB);
    ushort* qa    = (ushort*)(ws + 96 * MiB);
    ushort* ka    = (ushort*)(ws + 160 * MiB);
    ushort* kTa   = (ushort*)(ws + 224 * MiB);
    ushort* vTa   = (ushort*)(ws + 288 * MiB);
    float*  rt    = (float*)(ws + 352 * MiB);
    ushort* KVc   = (ushort*)(ws + 353 * MiB);
    ushort* KVbf  = (ushort*)(ws + 224 * MiB);
    ushort* attn  = (ushort*)(ws + 32 * MiB);
    ushort* nrm   = (ushort*)(ws + 96 * MiB);

    k_cvt<<<32768, 256, 0, stream>>>(x, xb, 8388608);
    dim3 gw(64, 64, 4);
    k_twt4<<<gw, 256, 0, stream>>>(Wq, Wk, Wv, Wo, WtQKV, WtK, WtV, WtO);
    k_rope<<<512, 256, 0, stream>>>(rt);

    // merged QKV GEMM + fused epilogue v1: 1536 blocks
    k_gemm<0><<<1536, 512, 0, stream>>>(xb, WtQKV, rt, nullptr, qa, ka, kTa, vTa);

    k_pass1<<<2048, 256, 0, stream>>>(kTa, vTa, KVc);
    k_scan<<<1024, 256, 0, stream>>>(KVc, KVbf);
    k_pass3<<<2048, 512, 0, stream>>>(qa, ka, vTa, KVbf, attn);

    k_rms<<<16384, 256, 0, stream>>>(attn, rmsw, nrm);
    // Wo GEMM: 512 blocks, proven m-band swizzle
    k_gemm<1><<<512, 512, 0, stream>>>(nrm, WtO, nullptr, (float*)d_out, nullptr, nullptr, nullptr, nullptr);
}

// Round 12
// 814.630 us; speedup vs baseline: 1.6529x; 1.6529x over previous
//
#include <hip/hip_runtime.h>

typedef unsigned short ushort;
typedef unsigned int uint;
typedef float f32x4 __attribute__((ext_vector_type(4)));
typedef __bf16 bf16x8 __attribute__((ext_vector_type(8)));
typedef ushort u16x4 __attribute__((ext_vector_type(4)));
typedef ushort u16x8 __attribute__((ext_vector_type(8)));

#define LOG2E 1.4426950408889634f

__device__ __forceinline__ ushort f2bu(float f) { __bf16 b = (__bf16)f; return __builtin_bit_cast(ushort, b); }
__device__ __forceinline__ float  bu2f(ushort u) { return (float)__builtin_bit_cast(__bf16, u); }

__device__ __forceinline__ void gld16(const void* g, void* l) {
    __builtin_amdgcn_global_load_lds((const __attribute__((address_space(1))) unsigned int*)g,
                                     (__attribute__((address_space(3))) unsigned int*)l, 16, 0, 0);
}

// ---------------- convert x fp32 -> bf16 ----------------
__global__ __launch_bounds__(256) void k_cvt(const float* __restrict__ in, ushort* __restrict__ out, int n4) {
    int i = blockIdx.x * 256 + threadIdx.x;
    if (i < n4) {
        float4 v = ((const float4*)in)[i];
        u16x4 o = { f2bu(v.x), f2bu(v.y), f2bu(v.z), f2bu(v.w) };
        ((u16x4*)out)[i] = o;
    }
}

// ---------------- transpose 4 weights fp32 [k][n] -> bf16 [n][k] (z selects) ----------------
__global__ __launch_bounds__(256) void k_twt4(const float* __restrict__ W0, const float* __restrict__ W1,
                                              const float* __restrict__ W2, const float* __restrict__ W3,
                                              ushort* __restrict__ D0, ushort* __restrict__ D1,
                                              ushort* __restrict__ D2, ushort* __restrict__ D3) {
    int z = blockIdx.z;
    const float* W = (z == 0) ? W0 : (z == 1) ? W1 : (z == 2) ? W2 : W3;
    ushort* Wt = (z == 0) ? D0 : (z == 1) ? D1 : (z == 2) ? D2 : D3;
    __shared__ float t[32][33];
    int n0 = blockIdx.x * 32, k0 = blockIdx.y * 32;
    int tx = threadIdx.x & 31, ty = threadIdx.x >> 5;
#pragma unroll
    for (int i = 0; i < 32; i += 8) t[ty + i][tx] = W[(size_t)(k0 + ty + i) * 2048 + n0 + tx];
    __syncthreads();
#pragma unroll
    for (int i = 0; i < 32; i += 8) Wt[(size_t)(n0 + ty + i) * 2048 + k0 + tx] = f2bu(t[tx][ty + i]);
}

// ---------------- rope cos/sin table [4096][32][2] ----------------
__global__ __launch_bounds__(256) void k_rope(float* __restrict__ tab) {
    int idx = blockIdx.x * 256 + threadIdx.x;   // 131072 total
    int t = idx >> 5, j = idx & 31;
    float fr = exp2f(-10.0f * (float)j / 31.0f);      // (1/1024)^(j/31)
    float th = (float)t * fr;
    tab[idx * 2]     = cosf(th);
    tab[idx * 2 + 1] = sinf(th);
}

// ============ 256x256 8-phase bf16 GEMM (m201 template, plain HIP) ============
// MODE 0: QKV merged (N=6144), fused rope/reshape epilogue — the ROUND-5
//   submission version, benched r6 at 492 us (row-major lt[128][258],
//   cid-group natural phase, u16x4 coalesced writes). n-panel XCD map:
//   nt = xcd + (local%3)*8.
// MODE 1: Wo (N=2048, f32 out), proven map m = xcd*8 + local>>3, n = local&7.
// K-loop (proven): BK=64 two kh halves, 8 waves (2Mx4N), LDS 128 KiB,
// staging swizzle chunk ^= (row>>1)&3, counted vmcnt(8) at ph2/ph4 tails.
#define AOFF(buf, kh) ((buf) * 32768 + (kh) * 16384)
#define BOFF(buf, kh) (65536 + (buf) * 32768 + (kh) * 16384)

#define STG_A(BUFX, KHX, KKX) do {                                                 \
    gld16(asrc0 + ((KKX) + (KHX) * 32) * 2, lds + AOFF(BUFX, KHX) + ldst);         \
    gld16(asrc1 + ((KKX) + (KHX) * 32) * 2, lds + AOFF(BUFX, KHX) + 8192 + ldst);  \
} while (0)
#define STG_B(BUFX, KHX, KKX) do {                                                 \
    gld16(bsrc0 + ((KKX) + (KHX) * 32) * 2, lds + BOFF(BUFX, KHX) + ldst);         \
    gld16(bsrc1 + ((KKX) + (KHX) * 32) * 2, lds + BOFF(BUFX, KHX) + 8192 + ldst);  \
} while (0)

#define PHASE(BUF, KH, MH, LDB, STAGE_STMT, TAILVM) do {                           \
    bf16x8 af_[4];                                                                 \
    const char* ab_ = lds + AOFF(BUF, KH);                                         \
    _Pragma("unroll")                                                              \
    for (int mi_ = 0; mi_ < 4; ++mi_)                                              \
        af_[mi_] = *(const bf16x8*)(ab_ + offA[(MH) * 4 + mi_]);                   \
    if (LDB) {                                                                     \
        const char* bb_ = lds + BOFF(BUF, KH);                                     \
        _Pragma("unroll")                                                          \
        for (int ni_ = 0; ni_ < 4; ++ni_)                                          \
            bfr[ni_] = *(const bf16x8*)(bb_ + offB[ni_]);                          \
    }                                                                              \
    STAGE_STMT;                                                                    \
    __builtin_amdgcn_s_barrier();                                                  \
    asm volatile("s_waitcnt lgkmcnt(0)" ::: "memory");                             \
    __builtin_amdgcn_sched_barrier(0);                                             \
    __builtin_amdgcn_s_setprio(1);                                                 \
    _Pragma("unroll")                                                              \
    for (int mi_ = 0; mi_ < 4; ++mi_)                                              \
        _Pragma("unroll")                                                          \
        for (int ni_ = 0; ni_ < 4; ++ni_)                                          \
            acc[(MH) * 4 + mi_][ni_] = __builtin_amdgcn_mfma_f32_16x16x32_bf16(    \
                af_[mi_], bfr[ni_], acc[(MH) * 4 + mi_][ni_], 0, 0, 0);            \
    __builtin_amdgcn_s_setprio(0);                                                 \
    TAILVM;                                                                        \
    __builtin_amdgcn_s_barrier();                                                  \
} while (0)

#define TILE(BUF, TC) do {                                                         \
    int tp1_ = (TC) + 1 < 32 ? (TC) + 1 : 31;                                      \
    int tp2_ = (TC) + 2 < 32 ? (TC) + 2 : 31;                                      \
    int kb1_ = tp1_ * 64, kb2_ = tp2_ * 64;                                        \
    PHASE(BUF, 0, 0, 1, STG_A((BUF) ^ 1, 1, kb1_), ((void)0));                     \
    PHASE(BUF, 0, 1, 0, STG_B((BUF) ^ 1, 1, kb1_),                                 \
          asm volatile("s_waitcnt vmcnt(8)" ::: "memory"));                        \
    PHASE(BUF, 1, 0, 1, STG_A(BUF, 0, kb2_), ((void)0));                           \
    PHASE(BUF, 1, 1, 0, STG_B(BUF, 0, kb2_),                                       \
          asm volatile("s_waitcnt vmcnt(8)" ::: "memory"));                        \
} while (0)

template <int MODE>
__global__ __launch_bounds__(512, 2) void k_gemm(const ushort* __restrict__ A, const ushort* __restrict__ Bt,
                                                 const float* __restrict__ rt, float* __restrict__ Cf,
                                                 ushort* __restrict__ qa, ushort* __restrict__ ka,
                                                 ushort* __restrict__ kTa, ushort* __restrict__ vTa) {
    __shared__ __align__(128) char lds[131072];
    const int tid = threadIdx.x;
    const int wid = tid >> 6, lane = tid & 63;
    const int wm = wid >> 2, wn = wid & 3;
    const int lrow = lane & 15, q = lane >> 4;

    int bid = blockIdx.x;
    int xcd = bid & 7, local = bid >> 3;
    int nt, mloc;
    if (MODE == 0) { nt = xcd + (local % 3) * 8; mloc = local / 3; }
    else           { nt = local & 7;             mloc = xcd * 8 + (local >> 3); }
    const size_t n0 = (size_t)nt * 256;
    const size_t m0 = (size_t)mloc * 256;

    // per-thread fragment ds_read byte offsets (staging swizzle)
    int offA[8], offB[4];
#pragma unroll
    for (int mi = 0; mi < 8; ++mi) {
        int R = wm * 128 + mi * 16 + lrow;
        offA[mi] = R * 64 + ((q ^ ((R >> 1) & 3)) << 4);
    }
#pragma unroll
    for (int ni = 0; ni < 4; ++ni) {
        int R = wn * 64 + ni * 16 + lrow;
        offB[ni] = R * 64 + ((q ^ ((R >> 1) & 3)) << 4);
    }

    int srow0 = tid >> 2;
    int cw = (tid & 3) ^ ((tid >> 3) & 3);
    const char* asrc0 = (const char*)(A + (m0 + srow0) * 2048 + cw * 8);
    const char* asrc1 = (const char*)(A + (m0 + srow0 + 128) * 2048 + cw * 8);
    const char* bsrc0 = (const char*)(Bt + (n0 + srow0) * 2048 + cw * 8);
    const char* bsrc1 = (const char*)(Bt + (n0 + srow0 + 128) * 2048 + cw * 8);
    const int ldst = tid * 16;

    f32x4 acc[8][4] = {};
    bf16x8 bfr[4];

    STG_A(0, 0, 0); STG_B(0, 0, 0); STG_A(0, 1, 0); STG_B(0, 1, 0);
    STG_A(1, 0, 64); STG_B(1, 0, 64);
    asm volatile("s_waitcnt vmcnt(8)" ::: "memory");
    __builtin_amdgcn_s_barrier();

#pragma unroll 1
    for (int t = 0; t < 32; t += 2) {
        TILE(0, t);
        TILE(1, t + 1);
    }

    if (MODE == 1) {
#pragma unroll
        for (int mi = 0; mi < 8; ++mi)
#pragma unroll
            for (int ni = 0; ni < 4; ++ni)
#pragma unroll
                for (int i = 0; i < 4; ++i) {
                    size_t row = m0 + wm * 128 + mi * 16 + q * 4 + i;
                    size_t col = n0 + wn * 64 + ni * 16 + lrow;
                    Cf[row * 2048 + col] = acc[mi][ni][i];
                }
        return;
    }

    // ---- MODE 0 fused epilogue (round-5 submission, benched r6 @492us) ----
    asm volatile("s_waitcnt vmcnt(0)" ::: "memory");   // drain tail gld_lds before LDS reuse
    __syncthreads();
    ushort* lt = (ushort*)lds;                 // [128][258]  (66 KB)
    const int tsel = nt >> 3;                  // 0 Q, 1 K, 2 V
    const int b = (int)(m0 >> 12);
    const int t0base = (int)(m0 & 4095);
    const int hbase = (nt & 7) * 2;

    for (int st = 0; st < 2; ++st) {
        if (wm == st) {
#pragma unroll
            for (int mi = 0; mi < 8; ++mi)
#pragma unroll
                for (int ni = 0; ni < 4; ++ni)
#pragma unroll
                    for (int i = 0; i < 4; ++i)
                        lt[(mi * 16 + q * 4 + i) * 258 + wn * 64 + ni * 16 + lrow] = f2bu(acc[mi][ni][i]);
        }
        __syncthreads();
        const int t0 = t0base + st * 128;
        if (tsel != 2) {
            // natural + rope: thread = cid(32, 4 cols) x rquad(16 rows); 16 iters
            int cid = tid & 31, rquad = tid >> 5;
            int d0 = cid * 4;
            ushort* dstN = (tsel == 0 ? qa : ka);
#pragma unroll 2
            for (int it = 0; it < 16; ++it) {
                int hl = it >> 3, rr = (it & 7) * 16 + rquad;
                int t = t0 + rr;
                const ushort* src = &lt[rr * 258 + hl * 128];
                ushort o[4];
                if (d0 < 32) {
#pragma unroll
                    for (int j = 0; j < 4; ++j) {
                        int d = d0 + j;
                        float2 cssn = *(const float2*)&rt[(t * 32 + d) * 2];
                        float x1 = bu2f(src[d]), x2 = bu2f(src[d + 64]);
                        o[j] = f2bu(x1 * cssn.x + x2 * cssn.y);
                    }
                } else if (d0 >= 64 && d0 < 96) {
#pragma unroll
                    for (int j = 0; j < 4; ++j) {
                        int d = d0 + j;
                        float2 cssn = *(const float2*)&rt[(t * 32 + (d - 64)) * 2];
                        float x1 = bu2f(src[d - 64]), x2 = bu2f(src[d]);
                        o[j] = f2bu(x2 * cssn.x - x1 * cssn.y);
                    }
                } else {
#pragma unroll
                    for (int j = 0; j < 4; ++j) o[j] = src[d0 + j];
                }
                int bh = b * 16 + hbase + hl;
                u16x4 ov = { o[0], o[1], o[2], o[3] };
                *(u16x4*)(dstN + ((size_t)bh * 4096 + t) * 128 + d0) = ov;
                if (tsel == 1 && (d0 < 32 || (d0 >= 64 && d0 < 96))) {
                    ushort* wb = &lt[rr * 258 + hl * 128 + d0];
                    wb[0] = o[0]; wb[1] = o[1]; wb[2] = o[2]; wb[3] = o[3];
                }
            }
        }
        if (tsel != 0) {
            __syncthreads();            // K: roped writeback visible; V: harmless
            int sb = tid & 31, dgrp = tid >> 5;
            int s0 = sb * 4;
            ushort* dstT = (tsel == 1 ? kTa : vTa);
#pragma unroll 2
            for (int it = 0; it < 16; ++it) {
                int hl = it >> 3, dd = (it & 7) * 16 + dgrp;
                int bh = b * 16 + hbase + hl;
                float l2r_h = -exp2f(-0.5f * (float)(hbase + hl + 1)) * LOG2E;
                ushort o[4];
#pragma unroll
                for (int j = 0; j < 4; ++j) {
                    int s = s0 + j;
                    float v = bu2f(lt[s * 258 + hl * 128 + dd]);
                    if (tsel == 1) v *= exp2f(l2r_h * (float)(127 - s));
                    o[j] = f2bu(v);
                }
                u16x4 ov = { o[0], o[1], o[2], o[3] };
                *(u16x4*)(dstT + ((size_t)bh * 128 + dd) * 4096 + t0 + s0) = ov;
            }
        }
        __syncthreads();
    }
}

// ---------------- pass1: chunk-local KVt[e][d] -> bf16 ----------------
__global__ __launch_bounds__(256) void k_pass1(const ushort* __restrict__ kTa, const ushort* __restrict__ vTa,
                                               ushort* __restrict__ KVc) {
    int blk = blockIdx.x;           // bh*32 + c
    int c = blk & 31, bh = blk >> 5;
    __shared__ __align__(16) ushort lv[128][136];
    __shared__ __align__(16) ushort lk[128][136];
    int tid = threadIdx.x;
#pragma unroll
    for (int i = 0; i < 8; ++i) {
        int idx = i * 256 + tid; int row = idx >> 4, cb = (idx & 15) * 8;
        *(bf16x8*)&lv[row][cb] = *(const bf16x8*)(vTa + ((size_t)bh * 128 + row) * 4096 + c * 128 + cb);
        *(bf16x8*)&lk[row][cb] = *(const bf16x8*)(kTa + ((size_t)bh * 128 + row) * 4096 + c * 128 + cb);
    }
    __syncthreads();
    int wid = tid >> 6, lane = tid & 63, wr = wid >> 1, wc = wid & 1;
    int lrow = lane & 15, lko = (lane >> 4) * 8;
    f32x4 acc[4][4] = {};
#pragma unroll
    for (int ks = 0; ks < 4; ++ks) {
        bf16x8 a[4], bb[4];
#pragma unroll
        for (int mi = 0; mi < 4; ++mi) a[mi] = *(const bf16x8*)&lv[wr * 64 + mi * 16 + lrow][ks * 32 + lko];
#pragma unroll
        for (int ni = 0; ni < 4; ++ni) bb[ni] = *(const bf16x8*)&lk[wc * 64 + ni * 16 + lrow][ks * 32 + lko];
#pragma unroll
        for (int mi = 0; mi < 4; ++mi)
#pragma unroll
            for (int ni = 0; ni < 4; ++ni)
                acc[mi][ni] = __builtin_amdgcn_mfma_f32_16x16x32_bf16(a[mi], bb[ni], acc[mi][ni], 0, 0, 0);
    }
    ushort* out = KVc + (size_t)blk * 16384;
#pragma unroll
    for (int mi = 0; mi < 4; ++mi)
#pragma unroll
        for (int ni = 0; ni < 4; ++ni)
#pragma unroll
            for (int i = 0; i < 4; ++i)
                out[(wr * 64 + mi * 16 + (lane >> 4) * 4 + i) * 128 + wc * 64 + ni * 16 + lrow] = f2bu(acc[mi][ni][i]);
}

// ---------------- pass2: prefix scan over chunks (fp32 state, bf16 in/out) ----------------
__global__ __launch_bounds__(256) void k_scan(const ushort* __restrict__ KVc, ushort* __restrict__ KVbf) {
    int bh = blockIdx.x >> 4, seg = blockIdx.x & 15, h = bh & 15;
    float slope = exp2f(-0.5f * (float)(h + 1));
    float rC = exp2f(-slope * LOG2E * 128.0f);
    int off = seg * 1024 + threadIdx.x * 4;
    f32x4 st = {0.f, 0.f, 0.f, 0.f};
    for (int c = 0; c < 32; ++c) {
        size_t base = ((size_t)bh * 32 + c) * 16384 + off;
        u16x4 vb = *(const u16x4*)(KVc + base);
        u16x4 o = { f2bu(st.x), f2bu(st.y), f2bu(st.z), f2bu(st.w) };
        *(u16x4*)(KVbf + base) = o;
        st.x = st.x * rC + bu2f(vb[0]);
        st.y = st.y * rC + bu2f(vb[1]);
        st.z = st.z * rC + bu2f(vb[2]);
        st.w = st.w * rC + bu2f(vb[3]);
    }
}

// ---------------- pass3: out = diag(q_decay)*(q@KV) + (dmask o (q@k^T))@v ----------------
__global__ __launch_bounds__(512) void k_pass3(const ushort* __restrict__ qa, const ushort* __restrict__ ka,
                                               const ushort* __restrict__ vTa, const ushort* __restrict__ KVbf,
                                               ushort* __restrict__ attn) {
    int blk = blockIdx.x;           // bh*32 + c
    int c = blk & 31, bh = blk >> 5, h = bh & 15;
    __shared__ __align__(16) ushort lq[128][136];
    __shared__ __align__(16) ushort lk[128][136];   // later reused as P
    __shared__ __align__(16) ushort lv[128][136];
    int tid = threadIdx.x;
#pragma unroll
    for (int i = 0; i < 4; ++i) {
        int idx = i * 512 + tid; int row = idx >> 4, cb = (idx & 15) * 8;
        *(bf16x8*)&lq[row][cb] = *(const bf16x8*)(qa + ((size_t)bh * 4096 + c * 128 + row) * 128 + cb);
        *(bf16x8*)&lk[row][cb] = *(const bf16x8*)(ka + ((size_t)bh * 4096 + c * 128 + row) * 128 + cb);
        *(bf16x8*)&lv[row][cb] = *(const bf16x8*)(vTa + ((size_t)bh * 128 + row) * 4096 + c * 128 + cb);
    }
    __syncthreads();
    int wid = tid >> 6, lane = tid & 63;
    int wr = wid >> 2, wc = wid & 3;          // 2 x 4 wave grid
    int lrow = lane & 15, lko = (lane >> 4) * 8;
    float slope = exp2f(-0.5f * (float)(h + 1));
    float l2r = -slope * LOG2E;

    f32x4 accs[4][2] = {};
#pragma unroll
    for (int kd = 0; kd < 4; ++kd) {
        bf16x8 a[4], bb[2];
#pragma unroll
        for (int mi = 0; mi < 4; ++mi) a[mi] = *(const bf16x8*)&lq[wr * 64 + mi * 16 + lrow][kd * 32 + lko];
#pragma unroll
        for (int ni = 0; ni < 2; ++ni) bb[ni] = *(const bf16x8*)&lk[wc * 32 + ni * 16 + lrow][kd * 32 + lko];
#pragma unroll
        for (int mi = 0; mi < 4; ++mi)
#pragma unroll
            for (int ni = 0; ni < 2; ++ni)
                accs[mi][ni] = __builtin_amdgcn_mfma_f32_16x16x32_bf16(a[mi], bb[ni], accs[mi][ni], 0, 0, 0);
    }
    __syncthreads();

    f32x4 acc[4][2] = {};
#pragma unroll
    for (int kd = 0; kd < 4; ++kd) {
        bf16x8 a[4], bb[2];
#pragma unroll
        for (int mi = 0; mi < 4; ++mi) a[mi] = *(const bf16x8*)&lq[wr * 64 + mi * 16 + lrow][kd * 32 + lko];
#pragma unroll
        for (int ni = 0; ni < 2; ++ni)
            bb[ni] = *(const bf16x8*)(KVbf + (size_t)blk * 16384 + (size_t)(wc * 32 + ni * 16 + lrow) * 128 + kd * 32 + lko);
#pragma unroll
        for (int mi = 0; mi < 4; ++mi)
#pragma unroll
            for (int ni = 0; ni < 2; ++ni)
                acc[mi][ni] = __builtin_amdgcn_mfma_f32_16x16x32_bf16(a[mi], bb[ni], acc[mi][ni], 0, 0, 0);
    }

#pragma unroll
    for (int mi = 0; mi < 4; ++mi)
#pragma unroll
        for (int ni = 0; ni < 2; ++ni)
#pragma unroll
            for (int i = 0; i < 4; ++i) {
                int t = wr * 64 + mi * 16 + (lane >> 4) * 4 + i;
                int s = wc * 32 + ni * 16 + lrow;
                int dt = t - s;
                float w = (dt < 0) ? 0.f : exp2f(l2r * (float)dt);
                lk[t][s] = f2bu(accs[mi][ni][i] * w);
            }

#pragma unroll
    for (int mi = 0; mi < 4; ++mi)
#pragma unroll
        for (int ni = 0; ni < 2; ++ni)
#pragma unroll
            for (int i = 0; i < 4; ++i) {
                int t = wr * 64 + mi * 16 + (lane >> 4) * 4 + i;
                acc[mi][ni][i] *= exp2f(l2r * (float)(t + 1));
            }
    __syncthreads();

#pragma unroll
    for (int ks = 0; ks < 4; ++ks) {
        bf16x8 a[4], bb[2];
#pragma unroll
        for (int mi = 0; mi < 4; ++mi) a[mi] = *(const bf16x8*)&lk[wr * 64 + mi * 16 + lrow][ks * 32 + lko];
#pragma unroll
        for (int ni = 0; ni < 2; ++ni) bb[ni] = *(const bf16x8*)&lv[wc * 32 + ni * 16 + lrow][ks * 32 + lko];
#pragma unroll
        for (int mi = 0; mi < 4; ++mi)
#pragma unroll
            for (int ni = 0; ni < 2; ++ni)
                acc[mi][ni] = __builtin_amdgcn_mfma_f32_16x16x32_bf16(a[mi], bb[ni], acc[mi][ni], 0, 0, 0);
    }

    ushort* out = attn + ((size_t)bh * 4096 + c * 128) * 128;
#pragma unroll
    for (int mi = 0; mi < 4; ++mi)
#pragma unroll
        for (int ni = 0; ni < 2; ++ni)
#pragma unroll
            for (int i = 0; i < 4; ++i)
                out[(size_t)(wr * 64 + mi * 16 + (lane >> 4) * 4 + i) * 128 + wc * 32 + ni * 16 + lrow] =
                    f2bu(acc[mi][ni][i]);
}

// ---------------- RMS norm + [b,h,t,d] -> [token][e] ----------------
__global__ __launch_bounds__(256) void k_rms(const ushort* __restrict__ attn, const float* __restrict__ w,
                                             ushort* __restrict__ normed) {
    int tok = blockIdx.x; int b = tok >> 12, t = tok & 4095;
    int tid = threadIdx.x;
    int e0 = tid * 8; int h = e0 >> 7, d0 = e0 & 127;
    bf16x8 v = *(const bf16x8*)(attn + (((size_t)(b * 16 + h) * 4096 + t) * 128 + d0));
    float f[8]; float ss = 0.f;
#pragma unroll
    for (int j = 0; j < 8; ++j) { f[j] = (float)v[j]; ss += f[j] * f[j]; }
#pragma unroll
    for (int o = 1; o < 64; o <<= 1) ss += __shfl_xor(ss, o, 64);
    __shared__ float red[4];
    if ((tid & 63) == 0) red[tid >> 6] = ss;
    __syncthreads();
    float tot = red[0] + red[1] + red[2] + red[3];
    float sc = rsqrtf(tot * (1.0f / 2048.0f) + 1e-5f);
    u16x8 ov;
#pragma unroll
    for (int j = 0; j < 8; ++j) ov[j] = f2bu(f[j] * sc * w[e0 + j]);
    *(u16x8*)(normed + (size_t)tok * 2048 + e0) = ov;
}

// ---------------- launch ----------------
// ws layout (MiB), lifetime-checked:
//   0-24    WtQKV (Q@0,K@8,V@16)  [twt4 -> QKV gemm]
//   24-32   WtO                   [twt4 -> Wo gemm]
//   32-96   xb [cvt -> QKV gemm] ; attn [pass3 -> rms]
//   96-160  qa  [QKV gemm -> pass3] ; nrm [rms -> Wo gemm]
//   160-224 ka  [QKV gemm -> pass3]
//   224-288 kTa [QKV gemm -> pass1] ; KVbf [scan -> pass3]
//   288-352 vTa [QKV gemm -> pass1,pass3]
//   352-353 rt  [rope -> QKV gemm]
//   353-417 KVc bf16 [pass1 -> scan]
// High-water 417 MiB.
extern "C" void kernel_launch(void* const* d_in, const int* in_sizes, int n_in,
                              void* d_out, int out_size, void* d_ws, size_t ws_size,
                              hipStream_t stream) {
    const float* x    = (const float*)d_in[0];
    const float* Wq   = (const float*)d_in[1];
    const float* Wk   = (const float*)d_in[2];
    const float* Wv   = (const float*)d_in[3];
    const float* Wo   = (const float*)d_in[4];
    const float* rmsw = (const float*)d_in[5];
    char* ws = (char*)d_ws;
    const size_t MiB = 1ull << 20;
    ushort* WtQKV = (ushort*)(ws + 0);
    ushort* WtK   = (ushort*)(ws + 8 * MiB);
    ushort* WtV   = (ushort*)(ws + 16 * MiB);
    ushort* WtO   = (ushort*)(ws + 24 * MiB);
    ushort* xb    = (ushort*)(ws + 32 * MiB);
    ushort* qa    = (ushort*)(ws + 96 * MiB);
    ushort* ka    = (ushort*)(ws + 160 * MiB);
    ushort* kTa   = (ushort*)(ws + 224 * MiB);
    ushort* vTa   = (ushort*)(ws + 288 * MiB);
    float*  rt    = (float*)(ws + 352 * MiB);
    ushort* KVc   = (ushort*)(ws + 353 * MiB);
    ushort* KVbf  = (ushort*)(ws + 224 * MiB);
    ushort* attn  = (ushort*)(ws + 32 * MiB);
    ushort* nrm   = (ushort*)(ws + 96 * MiB);

    k_cvt<<<32768, 256, 0, stream>>>(x, xb, 8388608);
    dim3 gw(64, 64, 4);
    k_twt4<<<gw, 256, 0, stream>>>(Wq, Wk, Wv, Wo, WtQKV, WtK, WtV, WtO);
    k_rope<<<512, 256, 0, stream>>>(rt);

    // merged QKV GEMM + fused epilogue (r6-benched version): 1536 blocks
    k_gemm<0><<<1536, 512, 0, stream>>>(xb, WtQKV, rt, nullptr, qa, ka, kTa, vTa);

    k_pass1<<<2048, 256, 0, stream>>>(kTa, vTa, KVc);
    k_scan<<<1024, 256, 0, stream>>>(KVc, KVbf);
    k_pass3<<<2048, 512, 0, stream>>>(qa, ka, vTa, KVbf, attn);

    k_rms<<<16384, 256, 0, stream>>>(attn, rmsw, nrm);
    // Wo GEMM: 512 blocks, proven m-band swizzle
    k_gemm<1><<<512, 512, 0, stream>>>(nrm, WtO, nullptr, (float*)d_out, nullptr, nullptr, nullptr, nullptr);
}